// Round 5
// baseline (280.341 us; speedup 1.0000x reference)
//
#include <hip/hip_runtime.h>
#include <cmath>

#define C_DIM 2048
#define B_DIM 16
#define H_DIM 16
#define HS_DIM 128
#define T_DIM 4096
#define ATT_SCALE 0.08838834764831845f  // 1/sqrt(128)
#define TCHUNK 512
#define NCHUNK (T_DIM / TCHUNK)         // 8 blocks per (b,h)

// ---------------------------------------------------------------------------
// Kernel 1 & 4: O[16, 2048] = X[16, 2048] @ W[2048, 2048]^T  (unchanged)
// ---------------------------------------------------------------------------
__global__ __launch_bounds__(256) void gemv16_kernel(
    const float* __restrict__ X, const float* __restrict__ W,
    float* __restrict__ O) {
  const int lane = threadIdx.x & 63;
  const int wave = threadIdx.x >> 6;            // 0..3
  const int n = blockIdx.x * 4 + wave;          // output column
  const float* wrow = W + (size_t)n * C_DIM;

  float acc[B_DIM];
#pragma unroll
  for (int m = 0; m < B_DIM; ++m) acc[m] = 0.f;

#pragma unroll
  for (int i = 0; i < C_DIM / 256; ++i) {
    const int j = i * 256 + lane * 4;
    const float4 w4 = *reinterpret_cast<const float4*>(wrow + j);
#pragma unroll
    for (int m = 0; m < B_DIM; ++m) {
      const float4 x4 = *reinterpret_cast<const float4*>(X + m * C_DIM + j);
      acc[m] += w4.x * x4.x + w4.y * x4.y + w4.z * x4.z + w4.w * x4.w;
    }
  }

#pragma unroll
  for (int m = 0; m < B_DIM; ++m) {
#pragma unroll
    for (int mask = 32; mask >= 1; mask >>= 1)
      acc[m] += __shfl_xor(acc[m], mask, 64);
  }
  if (lane == 0) {
#pragma unroll
    for (int m = 0; m < B_DIM; ++m) O[(size_t)m * C_DIM + n] = acc[m];
  }
}

// ---------------------------------------------------------------------------
// Kernel 2: attention partials. Grid = B*H*NCHUNK = 2048 blocks, 256 threads.
// Each (wave,half) unit owns 64 interleaved rows with private online softmax;
// 8 units merge via LDS into one block partial (pm, pl, py[128]).
// ---------------------------------------------------------------------------
__global__ __launch_bounds__(256, 6) void attn_partial_kernel(
    const float* __restrict__ q, const float* __restrict__ k,
    const float* __restrict__ v, float* __restrict__ pm,
    float* __restrict__ pl, float* __restrict__ py) {
  const int blk = blockIdx.x;                   // bh*NCHUNK + chunk
  const int bh = blk >> 3;
  const int chunk = blk & 7;
  const int lane = threadIdx.x & 63;
  const int wave = threadIdx.x >> 6;            // 0..3
  const int half = lane >> 5;
  const int dl = lane & 31;                     // dim-quad index
  const int unit = wave * 2 + half;             // 0..7

  const float4* kp = reinterpret_cast<const float4*>(k + (size_t)bh * T_DIM * HS_DIM);
  const float4* vp = reinterpret_cast<const float4*>(v + (size_t)bh * T_DIM * HS_DIM);
  const float4 qv = reinterpret_cast<const float4*>(q + (size_t)bh * HS_DIM)[dl];

  float m = -INFINITY, l = 0.f;
  float y0 = 0.f, y1 = 0.f, y2 = 0.f, y3 = 0.f;
  const int tbase = chunk * TCHUNK + unit;      // rows: tbase + 8*ti

#pragma unroll 4
  for (int ti = 0; ti < TCHUNK / 8; ++ti) {     // 64 iters, 1 row/unit/iter
    const int t = tbase + ti * 8;
    const float4 kv = kp[(size_t)t * 32 + dl];
    const float4 vv = vp[(size_t)t * 32 + dl];
    float p = kv.x * qv.x + kv.y * qv.y + kv.z * qv.z + kv.w * qv.w;
#pragma unroll
    for (int mask = 16; mask >= 1; mask >>= 1) p += __shfl_xor(p, mask, 64);
    const float s = p * ATT_SCALE;
    const float mn = fmaxf(m, s);
    const float c = __expf(m - mn);             // exp(-inf)=0 on first iter
    const float e = __expf(s - mn);
    l = l * c + e;
    y0 = fmaf(y0, c, e * vv.x);
    y1 = fmaf(y1, c, e * vv.y);
    y2 = fmaf(y2, c, e * vv.z);
    y3 = fmaf(y3, c, e * vv.w);
    m = mn;
  }

  __shared__ float lm[8];
  __shared__ float ll[8];
  __shared__ float ly[8 * HS_DIM];
  reinterpret_cast<float4*>(ly)[unit * 32 + dl] = make_float4(y0, y1, y2, y3);
  if (dl == 0) { lm[unit] = m; ll[unit] = l; }
  __syncthreads();

  const int tid = threadIdx.x;
  if (tid < HS_DIM) {
    float gm = lm[0];
#pragma unroll
    for (int u = 1; u < 8; ++u) gm = fmaxf(gm, lm[u]);
    float L = 0.f, yd = 0.f;
#pragma unroll
    for (int u = 0; u < 8; ++u) {
      const float e = __expf(lm[u] - gm);
      L = fmaf(e, ll[u], L);
      yd = fmaf(e, ly[u * HS_DIM + tid], yd);
    }
    py[(size_t)blk * HS_DIM + tid] = yd;
    if (tid == 0) { pm[blk] = gm; pl[blk] = L; }
  }
}

// ---------------------------------------------------------------------------
// Kernel 3: merge NCHUNK partials per (b,h). Grid 256, 128 threads.
// ---------------------------------------------------------------------------
__global__ __launch_bounds__(128) void attn_combine_kernel(
    const float* __restrict__ pm, const float* __restrict__ pl,
    const float* __restrict__ py, float* __restrict__ y) {
  const int bh = blockIdx.x;
  const int d = threadIdx.x;
  float gm = -INFINITY;
#pragma unroll
  for (int c = 0; c < NCHUNK; ++c) gm = fmaxf(gm, pm[bh * NCHUNK + c]);
  float L = 0.f, yd = 0.f;
#pragma unroll
  for (int c = 0; c < NCHUNK; ++c) {
    const float e = __expf(pm[bh * NCHUNK + c] - gm);
    L = fmaf(e, pl[bh * NCHUNK + c], L);
    yd = fmaf(e, py[(size_t)(bh * NCHUNK + c) * HS_DIM + d], yd);
  }
  y[(size_t)bh * HS_DIM + d] = yd / L;
}

extern "C" void kernel_launch(void* const* d_in, const int* in_sizes, int n_in,
                              void* d_out, int out_size, void* d_ws, size_t ws_size,
                              hipStream_t stream) {
  const float* x  = (const float*)d_in[0];   // [16, 1, 2048]
  const float* k  = (const float*)d_in[1];   // [16, 16, 4096, 128]
  const float* v  = (const float*)d_in[2];   // [16, 16, 4096, 128]
  const float* Wq = (const float*)d_in[3];   // [2048, 2048]
  const float* Wp = (const float*)d_in[4];   // [2048, 2048]
  float* out = (float*)d_out;                // [16, 1, 2048]

  float* ws   = (float*)d_ws;
  float* q_ws = ws;                          // [16, 2048]
  float* y_ws = ws + B_DIM * C_DIM;          // [16, 2048]
  float* pm   = y_ws + B_DIM * C_DIM;        // [2048]
  float* pl   = pm + B_DIM * H_DIM * NCHUNK; // [2048]
  float* py   = pl + B_DIM * H_DIM * NCHUNK; // [2048 * 128]

  hipLaunchKernelGGL(gemv16_kernel, dim3(C_DIM / 4), dim3(256), 0, stream,
                     x, Wq, q_ws);
  hipLaunchKernelGGL(attn_partial_kernel, dim3(B_DIM * H_DIM * NCHUNK), dim3(256), 0, stream,
                     q_ws, k, v, pm, pl, py);
  hipLaunchKernelGGL(attn_combine_kernel, dim3(B_DIM * H_DIM), dim3(128), 0, stream,
                     pm, pl, py, y_ws);
  hipLaunchKernelGGL(gemv16_kernel, dim3(C_DIM / 4), dim3(256), 0, stream,
                     y_ws, Wp, out);
}